// Round 8
// baseline (187.278 us; speedup 1.0000x reference)
//
#include <hip/hip_runtime.h>
#include <math.h>

#define N_LEAVES 65536
#define WAVES 24
#define WC 2048
#define KSPLITS 3
#define S 128
#define N_INT (WAVES * WC)   // 49152 internal clades
#define G 2048
#define E_ITERS 50
#define EPS 1e-30f

#define NBLK 1024
#define TPB 512   // 8 wavefronts/block; 1024*8 = 8192 wavefronts = 4 per clade slot
                  // = 32 waves/CU = hardware occupancy ceiling

#define AGENT __HIP_MEMORY_SCOPE_AGENT
#define SENT8 0xFFFFFFFFFFFFFFFFull
#define SENT4 0xFFFFFFFFu

union F2U { float2 f; unsigned long long u; };

// ---------------------------------------------------------------------------
// init: sentinel-fill P (25.2 MB) and meta (rsum,ls pairs); zero out.
// P holds probabilities in [0,1], meta holds finite reals -> the all-ones
// (NaN) pattern can never be produced by real data: data IS the ready flag.
// ---------------------------------------------------------------------------
__global__ __launch_bounds__(256) void init_kernel(uint4* __restrict__ P4,
                                                   unsigned long long* __restrict__ meta,
                                                   float* __restrict__ out) {
    const int NP4 = N_INT * S / 4;   // 1,572,864 uint4
    int idx = blockIdx.x * 256 + threadIdx.x;
    int stride = gridDim.x * 256;
    uint4 s4 = make_uint4(SENT4, SENT4, SENT4, SENT4);
    for (int i = idx; i < NP4; i += stride) P4[i] = s4;
    for (int i = idx; i < N_INT; i += stride) meta[i] = SENT8;
    if (idx == 0) out[0] = 0.0f;
}

__device__ __forceinline__ unsigned long long frag_load(const float* __restrict__ P,
                                                        int r, int lane) {
    return __hip_atomic_load((const unsigned long long*)(P + (size_t)r * S) + lane,
                             __ATOMIC_RELAXED, AGENT);
}
__device__ __forceinline__ float rsum_load(const unsigned long long* __restrict__ meta,
                                           int r) {
    unsigned u = __hip_atomic_load((const unsigned*)(meta + r), __ATOMIC_RELAXED, AGENT);
    return __uint_as_float(u);
}

// ---- per-slot state (named vars, compile-time indices -> registers) --------
#define SLOT_DECL(Sx)                                                          \
  float2 pv##Sx[6]; float rs##Sx[6]; int pidx##Sx[6]; float wq##Sx[3];         \
  int pend##Sx = 0, leafm##Sx = 0;

// refill slot with wave KK (guarded): load indices + logits, softmax,
// classify children, ISSUE all gathers. Leaf species stashed in pidx.
#define REFILL(Sx, KK)                                                         \
  {                                                                            \
    const int kk_ = (KK);                                                      \
    if (kk_ < WAVES) {                                                         \
      const int b_ = (kk_ * WC + c) * KSPLITS;                                 \
      const int lo_ = N_LEAVES + kk_ * WC;                                     \
      float l0_ = logw[b_], l1_ = logw[b_ + 1], l2_ = logw[b_ + 2];            \
      float m_ = fmaxf(l0_, fmaxf(l1_, l2_));                                  \
      float e0_ = expf(l0_ - m_), e1_ = expf(l1_ - m_), e2_ = expf(l2_ - m_);  \
      float inv_ = 1.0f / (e0_ + e1_ + e2_);                                   \
      wq##Sx[0] = e0_ * inv_; wq##Sx[1] = e1_ * inv_; wq##Sx[2] = e2_ * inv_;  \
      pend##Sx = 0; leafm##Sx = 0;                                             \
      _Pragma("unroll")                                                        \
      for (int j_ = 0; j_ < 6; ++j_) {                                         \
        int idx_ = (j_ < 3) ? left[b_ + j_] : right[b_ + j_ - 3];              \
        float2 v_ = make_float2(0.f, 0.f);                                     \
        float rs_ = 0.f;                                                       \
        if (idx_ < N_LEAVES) {                                                 \
          leafm##Sx |= 1 << j_;                                                \
          idx_ = leaf_species[idx_];                                           \
        } else if (idx_ < lo_) {                                               \
          pend##Sx |= 1 << j_;                                                 \
          int r_ = idx_ - N_LEAVES;                                            \
          F2U u_; u_.u = frag_load(P, r_, lane);                               \
          v_ = u_.f;                                                           \
          rs_ = rsum_load(meta, r_);                                           \
        }                                                                      \
        pidx##Sx[j_] = idx_; pv##Sx[j_] = v_; rs##Sx[j_] = rs_;                \
      }                                                                        \
    }                                                                          \
  }

// spin until all of the slot's pending children are resolved
#define RESOLVE_SPIN(Sx)                                                       \
  while (pend##Sx) {                                                           \
    int done_ = 0;                                                             \
    _Pragma("unroll")                                                          \
    for (int j_ = 0; j_ < 6; ++j_)                                             \
      if ((pend##Sx >> j_) & 1) {                                              \
        int r_ = pidx##Sx[j_] - N_LEAVES;                                      \
        F2U u_; u_.f = pv##Sx[j_];                                             \
        if (u_.u == SENT8) { u_.u = frag_load(P, r_, lane); pv##Sx[j_] = u_.f; } \
        if (__float_as_uint(rs##Sx[j_]) == SENT4)                              \
          rs##Sx[j_] = rsum_load(meta, r_);                                    \
        if (__all((u_.u != SENT8) && (__float_as_uint(rs##Sx[j_]) != SENT4)))  \
          done_ |= 1 << j_;                                                    \
      }                                                                        \
    pend##Sx &= ~done_;                                                        \
    if (pend##Sx) __builtin_amdgcn_s_sleep(1);                                 \
  }

// compute + publish wave KK from a fully-resolved slot (bit-identical to r4)
#define FIRE(Sx, KK)                                                           \
  {                                                                            \
    _Pragma("unroll")                                                          \
    for (int j_ = 0; j_ < 6; ++j_)                                             \
      if ((leafm##Sx >> j_) & 1) {                                             \
        int sp_ = pidx##Sx[j_];                                                \
        pv##Sx[j_].x = (sp_ == 2 * lane) ? 1.f : 0.f;                          \
        pv##Sx[j_].y = (sp_ == 2 * lane + 1) ? 1.f : 0.f;                      \
        rs##Sx[j_] = 1.f;                                                      \
      }                                                                        \
    float v0_ = 0.f, v1_ = 0.f;                                                \
    _Pragma("unroll")                                                          \
    for (int jj_ = 0; jj_ < KSPLITS; ++jj_) {                                  \
      float2 a_ = pv##Sx[jj_], b_ = pv##Sx[jj_ + 3];                           \
      float sl_ = rs##Sx[jj_], sr_ = rs##Sx[jj_ + 3], w_ = wq##Sx[jj_];        \
      v0_ += w_ * (onepD * a_.x * b_.x +                                       \
                   T127 * (a_.x * (sr_ - b_.x) + b_.x * (sl_ - a_.x)));        \
      v1_ += w_ * (onepD * a_.y * b_.y +                                       \
                   T127 * (a_.y * (sr_ - b_.y) + b_.y * (sl_ - a_.y)));        \
    }                                                                          \
    v0_ /= denom; v1_ /= denom;                                                \
    float mx_ = fmaxf(v0_, v1_);                                               \
    float tt_ = v0_ + v1_;                                                     \
    _Pragma("unroll")                                                          \
    for (int d_ = 1; d_ < 64; d_ <<= 1) {                                      \
      mx_ = fmaxf(mx_, __shfl_xor(mx_, d_));                                   \
      tt_ += __shfl_xor(tt_, d_);                                              \
    }                                                                          \
    const float safe_ = fmaxf(mx_, EPS);                                       \
    const int row_ = (KK) * WC + c;                                            \
    F2U o_; o_.f = make_float2(v0_ / safe_, v1_ / safe_);                      \
    __hip_atomic_store((unsigned long long*)(P + (size_t)row_ * S) + lane,     \
                       o_.u, __ATOMIC_RELAXED, AGENT);                         \
    if (lane == 0) {                                                           \
      F2U mo_; mo_.f = make_float2(tt_ / safe_, logf(safe_));                  \
      __hip_atomic_store(&meta[row_], mo_.u, __ATOMIC_RELAXED, AGENT);         \
    }                                                                          \
  }

// ---------------------------------------------------------------------------
// fused: 8192 wavefronts (4 per clade slot, 4-way wave split) = 32 waves/CU,
// the hardware occupancy ceiling. Waves of one slot are independent clades
// -> splitting them costs no communication; IF round-trip stalls hide under
// 4x the independent resident work. Two-slot ping-pong, in-order fire.
// ---------------------------------------------------------------------------
__global__ __launch_bounds__(TPB, 8) void fused_kernel(
    const float* __restrict__ theta, const float* __restrict__ logw,
    const int* __restrict__ left, const int* __restrict__ right,
    const int* __restrict__ leaf_species, const int* __restrict__ root_ids,
    float* __restrict__ P, unsigned long long* __restrict__ meta,
    float* __restrict__ out) {
    const int lane = threadIdx.x & 63;
    const int w = blockIdx.x * (TPB / 64) + (threadIdx.x >> 6);  // 0..8191
    const int c = w >> 2;        // clade slot 0..2047
    const int q = w & 3;         // wave phase 0..3

    // DTL rates + extinction fixed point (e uniform across species ->
    // mean(e) == e bitwise; scalar iteration).
    const float D = exp2f(theta[0]);
    const float L = exp2f(theta[1]);
    const float T = exp2f(theta[2]);
    const float norm = D + L + T + 1.0f;
    float e = L / norm;
#pragma unroll 1
    for (int i = 0; i < E_ITERS; ++i)
        e = (L + D * e * e + T * e * e) / norm;
    const float denom = 1.0f + D * e + T * e;
    const float onepD = 1.0f + D;
    const float T127 = T / 127.0f;

    SLOT_DECL(A) SLOT_DECL(B)

    REFILL(A, q) REFILL(B, q + 4)

#pragma unroll 1
    for (int k = q; k < WAVES; k += 8) {
        RESOLVE_SPIN(A) FIRE(A, k)     REFILL(A, k + 8)
        RESOLVE_SPIN(B) FIRE(B, k + 4) REFILL(B, k + 12)
    }

    // final: per-family ll from the root row's meta (rsum, ls) — one 8B poll
    // (single-copy-atomic publish => both words flip together). Leaf roots
    // contribute exactly 0 — skipped bitwise. Phase-0 wavefront of slot c
    // handles family c.
    const int r = root_ids[c];
    if (q == 0 && r >= N_LEAVES && lane == 0) {
        const int row = r - N_LEAVES;
        F2U m;
        while ((m.u = __hip_atomic_load(&meta[row], __ATOMIC_RELAXED, AGENT)) == SENT8)
            __builtin_amdgcn_s_sleep(1);
        atomicAdd(out, -(logf(m.f.x + EPS) + m.f.y));
    }
}

// ---------------------------------------------------------------------------
extern "C" void kernel_launch(void* const* d_in, const int* in_sizes, int n_in,
                              void* d_out, int out_size, void* d_ws, size_t ws_size,
                              hipStream_t stream) {
    const float* theta        = (const float*)d_in[0];
    const float* logw         = (const float*)d_in[1];
    const int*   left         = (const int*)d_in[2];
    const int*   right        = (const int*)d_in[3];
    const int*   leaf_species = (const int*)d_in[4];
    const int*   root_ids     = (const int*)d_in[5];
    float* out = (float*)d_out;

    char* ws = (char*)d_ws;
    float* P = (float*)ws;                                        // 25.17 MB
    unsigned long long* meta =
        (unsigned long long*)(ws + (size_t)N_INT * S * 4);        // 0.39 MB

    init_kernel<<<2048, 256, 0, stream>>>((uint4*)P, meta, out);
    fused_kernel<<<NBLK, TPB, 0, stream>>>(theta, logw, left, right,
                                           leaf_species, root_ids,
                                           P, meta, out);
}

// Round 9
// 73.593 us; speedup vs baseline: 2.5448x; 2.5448x over previous
//
#include <hip/hip_runtime.h>
#include <math.h>

#define N_LEAVES 65536
#define WAVES 24
#define WC 2048
#define KSPLITS 3
#define S 128
#define N_INT (WAVES * WC)   // 49152 internal clades
#define G 2048
#define E_ITERS 50
#define EPS 1e-30f

#define NBLK 768
#define TPB 512   // 8 wavefronts/block; 768*8 = 6144 wavefronts = 3 per clade slot
                  // = 24 waves/CU (6/EU): occupancy step below the r8 spill cliff

#define AGENT __HIP_MEMORY_SCOPE_AGENT
#define SENT8 0xFFFFFFFFFFFFFFFFull
#define SENT4 0xFFFFFFFFu

union F2U { float2 f; unsigned long long u; };

// ---------------------------------------------------------------------------
// init: sentinel-fill P (25.2 MB) and meta (rsum,ls pairs); zero out.
// P holds probabilities in [0,1], meta holds finite reals -> the all-ones
// (NaN) pattern can never be produced by real data: data IS the ready flag.
// ---------------------------------------------------------------------------
__global__ __launch_bounds__(256) void init_kernel(uint4* __restrict__ P4,
                                                   unsigned long long* __restrict__ meta,
                                                   float* __restrict__ out) {
    const int NP4 = N_INT * S / 4;   // 1,572,864 uint4
    int idx = blockIdx.x * 256 + threadIdx.x;
    int stride = gridDim.x * 256;
    uint4 s4 = make_uint4(SENT4, SENT4, SENT4, SENT4);
    for (int i = idx; i < NP4; i += stride) P4[i] = s4;
    for (int i = idx; i < N_INT; i += stride) meta[i] = SENT8;
    if (idx == 0) out[0] = 0.0f;
}

__device__ __forceinline__ unsigned long long frag_load(const float* __restrict__ P,
                                                        int r, int lane) {
    return __hip_atomic_load((const unsigned long long*)(P + (size_t)r * S) + lane,
                             __ATOMIC_RELAXED, AGENT);
}
__device__ __forceinline__ float rsum_load(const unsigned long long* __restrict__ meta,
                                           int r) {
    unsigned u = __hip_atomic_load((const unsigned*)(meta + r), __ATOMIC_RELAXED, AGENT);
    return __uint_as_float(u);
}

// ---- per-slot state (minimized: ~23 VGPR/slot; child indices are NOT kept —
// ---- the rare resolve path reloads them from L1-hot left/right) ------------
#define SLOT_DECL(Sx)                                                          \
  float2 pv##Sx[6]; float rs##Sx[6]; float wq##Sx[3];                          \
  int pend##Sx = 0, base##Sx = 0;

// refill slot with wave KK (guarded): softmax, classify children, leaf
// one-hots built IMMEDIATELY (no deferred species), gathers ISSUED.
#define REFILL(Sx, KK)                                                         \
  {                                                                            \
    const int kk_ = (KK);                                                      \
    if (kk_ < WAVES) {                                                         \
      const int b_ = (kk_ * WC + c) * KSPLITS;                                 \
      base##Sx = b_;                                                           \
      const int lo_ = N_LEAVES + kk_ * WC;                                     \
      float l0_ = logw[b_], l1_ = logw[b_ + 1], l2_ = logw[b_ + 2];            \
      float m_ = fmaxf(l0_, fmaxf(l1_, l2_));                                  \
      float e0_ = expf(l0_ - m_), e1_ = expf(l1_ - m_), e2_ = expf(l2_ - m_);  \
      float inv_ = 1.0f / (e0_ + e1_ + e2_);                                   \
      wq##Sx[0] = e0_ * inv_; wq##Sx[1] = e1_ * inv_; wq##Sx[2] = e2_ * inv_;  \
      pend##Sx = 0;                                                            \
      _Pragma("unroll")                                                        \
      for (int j_ = 0; j_ < 6; ++j_) {                                         \
        int idx_ = (j_ < 3) ? left[b_ + j_] : right[b_ + j_ - 3];              \
        float2 v_ = make_float2(0.f, 0.f);                                     \
        float rs_ = 0.f;                                                       \
        if (idx_ < N_LEAVES) {                                                 \
          int sp_ = leaf_species[idx_];                                        \
          v_.x = (sp_ == 2 * lane) ? 1.f : 0.f;                                \
          v_.y = (sp_ == 2 * lane + 1) ? 1.f : 0.f;                            \
          rs_ = 1.f;                                                           \
        } else if (idx_ < lo_) {                                               \
          pend##Sx |= 1 << j_;                                                 \
          int r_ = idx_ - N_LEAVES;                                            \
          F2U u_; u_.u = frag_load(P, r_, lane);                               \
          v_ = u_.f;                                                           \
          rs_ = rsum_load(meta, r_);                                           \
        }                                                                      \
        pv##Sx[j_] = v_; rs##Sx[j_] = rs_;                                     \
      }                                                                        \
    }                                                                          \
  }

// spin until pending children resolve (reload child index from L1-hot arrays)
#define RESOLVE_SPIN(Sx)                                                       \
  while (pend##Sx) {                                                           \
    int done_ = 0;                                                             \
    _Pragma("unroll")                                                          \
    for (int j_ = 0; j_ < 6; ++j_)                                             \
      if ((pend##Sx >> j_) & 1) {                                              \
        int idx_ = (j_ < 3) ? left[base##Sx + j_] : right[base##Sx + j_ - 3];  \
        int r_ = idx_ - N_LEAVES;                                              \
        F2U u_; u_.f = pv##Sx[j_];                                             \
        if (u_.u == SENT8) { u_.u = frag_load(P, r_, lane); pv##Sx[j_] = u_.f; } \
        if (__float_as_uint(rs##Sx[j_]) == SENT4)                              \
          rs##Sx[j_] = rsum_load(meta, r_);                                    \
        if (__all((u_.u != SENT8) && (__float_as_uint(rs##Sx[j_]) != SENT4)))  \
          done_ |= 1 << j_;                                                    \
      }                                                                        \
    pend##Sx &= ~done_;                                                        \
    if (pend##Sx) __builtin_amdgcn_s_sleep(1);                                 \
  }

// compute + publish wave KK from a fully-resolved slot (math identical to r4)
#define FIRE(Sx, KK)                                                           \
  {                                                                            \
    float v0_ = 0.f, v1_ = 0.f;                                                \
    _Pragma("unroll")                                                          \
    for (int jj_ = 0; jj_ < KSPLITS; ++jj_) {                                  \
      float2 a_ = pv##Sx[jj_], b_ = pv##Sx[jj_ + 3];                           \
      float sl_ = rs##Sx[jj_], sr_ = rs##Sx[jj_ + 3], w_ = wq##Sx[jj_];        \
      v0_ += w_ * (onepD * a_.x * b_.x +                                       \
                   T127 * (a_.x * (sr_ - b_.x) + b_.x * (sl_ - a_.x)));        \
      v1_ += w_ * (onepD * a_.y * b_.y +                                       \
                   T127 * (a_.y * (sr_ - b_.y) + b_.y * (sl_ - a_.y)));        \
    }                                                                          \
    v0_ /= denom; v1_ /= denom;                                                \
    float mx_ = fmaxf(v0_, v1_);                                               \
    float tt_ = v0_ + v1_;                                                     \
    _Pragma("unroll")                                                          \
    for (int d_ = 1; d_ < 64; d_ <<= 1) {                                      \
      mx_ = fmaxf(mx_, __shfl_xor(mx_, d_));                                   \
      tt_ += __shfl_xor(tt_, d_);                                              \
    }                                                                          \
    const float safe_ = fmaxf(mx_, EPS);                                       \
    const int row_ = (KK) * WC + c;                                            \
    F2U o_; o_.f = make_float2(v0_ / safe_, v1_ / safe_);                      \
    __hip_atomic_store((unsigned long long*)(P + (size_t)row_ * S) + lane,     \
                       o_.u, __ATOMIC_RELAXED, AGENT);                         \
    if (lane == 0) {                                                           \
      F2U mo_; mo_.f = make_float2(tt_ / safe_, logf(safe_));                  \
      __hip_atomic_store(&meta[row_], mo_.u, __ATOMIC_RELAXED, AGENT);         \
    }                                                                          \
  }

// ---------------------------------------------------------------------------
// fused: 6144 wavefronts (3 per clade slot) = 24 waves/CU (6/EU) — the
// occupancy step between r7 (4/EU, 56 VGPR, latency-starved) and r8 (8/EU,
// spill storm). Slot state minimized to fit the ~84-reg budget of 6/EU.
// Two-slot ping-pong, in-order fire per wavefront (deadlock-free).
// ---------------------------------------------------------------------------
__global__ __launch_bounds__(TPB, 6) void fused_kernel(
    const float* __restrict__ theta, const float* __restrict__ logw,
    const int* __restrict__ left, const int* __restrict__ right,
    const int* __restrict__ leaf_species, const int* __restrict__ root_ids,
    float* __restrict__ P, unsigned long long* __restrict__ meta,
    float* __restrict__ out) {
    const int lane = threadIdx.x & 63;
    const int w = blockIdx.x * (TPB / 64) + (threadIdx.x >> 6);  // 0..6143
    const int c = w / 3;         // clade slot 0..2047
    const int q = w - 3 * c;     // wave phase 0..2

    // DTL rates + extinction fixed point (e uniform across species ->
    // mean(e) == e bitwise; scalar iteration).
    const float D = exp2f(theta[0]);
    const float L = exp2f(theta[1]);
    const float T = exp2f(theta[2]);
    const float norm = D + L + T + 1.0f;
    float e = L / norm;
#pragma unroll 1
    for (int i = 0; i < E_ITERS; ++i)
        e = (L + D * e * e + T * e * e) / norm;
    const float denom = 1.0f + D * e + T * e;
    const float onepD = 1.0f + D;
    const float T127 = T / 127.0f;

    SLOT_DECL(A) SLOT_DECL(B)

    REFILL(A, q) REFILL(B, q + 3)

#pragma unroll 1
    for (int k = q; k < WAVES; k += 6) {
        RESOLVE_SPIN(A) FIRE(A, k)     REFILL(A, k + 6)
        RESOLVE_SPIN(B) FIRE(B, k + 3) REFILL(B, k + 9)
    }

    // final: per-family ll from the root row's meta (rsum, ls) — one 8B poll
    // (single-copy-atomic publish => both words flip together). Leaf roots
    // contribute exactly 0 — skipped bitwise. Phase-0 wavefront of slot c
    // handles family c.
    const int r = root_ids[c];
    if (q == 0 && r >= N_LEAVES && lane == 0) {
        const int row = r - N_LEAVES;
        F2U m;
        while ((m.u = __hip_atomic_load(&meta[row], __ATOMIC_RELAXED, AGENT)) == SENT8)
            __builtin_amdgcn_s_sleep(1);
        atomicAdd(out, -(logf(m.f.x + EPS) + m.f.y));
    }
}

// ---------------------------------------------------------------------------
extern "C" void kernel_launch(void* const* d_in, const int* in_sizes, int n_in,
                              void* d_out, int out_size, void* d_ws, size_t ws_size,
                              hipStream_t stream) {
    const float* theta        = (const float*)d_in[0];
    const float* logw         = (const float*)d_in[1];
    const int*   left         = (const int*)d_in[2];
    const int*   right        = (const int*)d_in[3];
    const int*   leaf_species = (const int*)d_in[4];
    const int*   root_ids     = (const int*)d_in[5];
    float* out = (float*)d_out;

    char* ws = (char*)d_ws;
    float* P = (float*)ws;                                        // 25.17 MB
    unsigned long long* meta =
        (unsigned long long*)(ws + (size_t)N_INT * S * 4);        // 0.39 MB

    init_kernel<<<2048, 256, 0, stream>>>((uint4*)P, meta, out);
    fused_kernel<<<NBLK, TPB, 0, stream>>>(theta, logw, left, right,
                                           leaf_species, root_ids,
                                           P, meta, out);
}

// Round 10
// 65.019 us; speedup vs baseline: 2.8803x; 1.1319x over previous
//
#include <hip/hip_runtime.h>
#include <math.h>

#define N_LEAVES 65536
#define WAVES 24
#define WC 2048
#define KSPLITS 3
#define S 128
#define N_INT (WAVES * WC)   // 49152 internal clades
#define G 2048
#define E_ITERS 50
#define EPS 1e-30f

#define NBLK 768
#define TPB 512   // 8 wavefronts/block; 768*8 = 6144 wavefronts = 3 per clade slot
                  // = 24 waves/CU (6/EU): best measured occupancy point (r9)

#define AGENT __HIP_MEMORY_SCOPE_AGENT
#define SENT8 0xFFFFFFFFFFFFFFFFull

union F2U { float2 f; unsigned long long u; };

// ---------------------------------------------------------------------------
// init: sentinel-fill ONLY meta (49152 x 8B = 0.39 MB) and zero out.
// P needs no init: row visibility is signaled by meta (producer drains row
// stores to the coherence point BEFORE setting meta), so stale prior-call
// P data can never be observed. meta holds finite (rsum, ls) floats ->
// the all-ones pattern can never be produced by real data.
// ---------------------------------------------------------------------------
__global__ __launch_bounds__(256) void init_kernel(unsigned long long* __restrict__ meta,
                                                   float* __restrict__ out) {
    int i = blockIdx.x * 256 + threadIdx.x;
    if (i < N_INT) meta[i] = SENT8;
    if (i == 0) out[0] = 0.0f;
}

// agent-scope (IF-coherent) loads
__device__ __forceinline__ unsigned long long meta_load(
    const unsigned long long* __restrict__ meta, int r) {
    return __hip_atomic_load(meta + r, __ATOMIC_RELAXED, AGENT);
}
// `dep` carries a data dependency on the observed meta value so the row
// gather cannot be hoisted above the meta observation.
__device__ __forceinline__ float2 row_gather(const float* __restrict__ P,
                                             int r, int lane, int dep) {
    F2U x;
    x.u = __hip_atomic_load(
        (const unsigned long long*)(P + (size_t)r * S) + (lane + dep),
        __ATOMIC_RELAXED, AGENT);
    return x.f;
}

// ---- per-slot state (~23 VGPR/slot; child indices reloaded from L1-hot
// ---- left/right on the rare resolve path) ----------------------------------
#define SLOT_DECL(Sx)                                                          \
  float2 pv##Sx[6]; float rs##Sx[6]; float wq##Sx[3];                          \
  int pend##Sx = 0, base##Sx = 0;

// refill slot with wave KK (guarded): softmax; batched meta/species loads
// (straight-line, no serialized RTTs); classify; leaf one-hots immediate;
// row gathers ISSUED for meta-ready children; meta-pending children deferred.
#define REFILL(Sx, KK)                                                         \
  {                                                                            \
    const int kk_ = (KK);                                                      \
    if (kk_ < WAVES) {                                                         \
      const int b_ = (kk_ * WC + c) * KSPLITS;                                 \
      base##Sx = b_;                                                           \
      const int lo_ = N_LEAVES + kk_ * WC;                                     \
      float l0_ = logw[b_], l1_ = logw[b_ + 1], l2_ = logw[b_ + 2];            \
      float m_ = fmaxf(l0_, fmaxf(l1_, l2_));                                  \
      float e0_ = expf(l0_ - m_), e1_ = expf(l1_ - m_), e2_ = expf(l2_ - m_);  \
      float inv_ = 1.0f / (e0_ + e1_ + e2_);                                   \
      wq##Sx[0] = e0_ * inv_; wq##Sx[1] = e1_ * inv_; wq##Sx[2] = e2_ * inv_;  \
      int idxv_[6]; int spv_[6]; unsigned long long mu_[6];                    \
      _Pragma("unroll")                                                        \
      for (int j_ = 0; j_ < 6; ++j_) {                                         \
        int idx_ = (j_ < 3) ? left[b_ + j_] : right[b_ + j_ - 3];              \
        idxv_[j_] = idx_;                                                      \
        int sidx_ = idx_ < N_LEAVES ? idx_ : 0;                                \
        spv_[j_] = leaf_species[sidx_];                                        \
        int rr_ = idx_ - N_LEAVES;                                             \
        rr_ = rr_ < 0 ? 0 : (rr_ >= N_INT ? N_INT - 1 : rr_);                  \
        mu_[j_] = meta_load(meta, rr_);                                        \
      }                                                                        \
      pend##Sx = 0;                                                            \
      _Pragma("unroll")                                                        \
      for (int j_ = 0; j_ < 6; ++j_) {                                         \
        int idx_ = idxv_[j_];                                                  \
        float2 v_ = make_float2(0.f, 0.f);                                     \
        float rs_ = 0.f;                                                       \
        if (idx_ < N_LEAVES) {                                                 \
          v_.x = (spv_[j_] == 2 * lane) ? 1.f : 0.f;                           \
          v_.y = (spv_[j_] == 2 * lane + 1) ? 1.f : 0.f;                       \
          rs_ = 1.f;                                                           \
        } else if (idx_ < lo_) {                                               \
          if (__all(mu_[j_] != SENT8)) {                                       \
            F2U mm_; mm_.u = mu_[j_];                                          \
            rs_ = mm_.f.x;                                                     \
            v_ = row_gather(P, idx_ - N_LEAVES, lane,                          \
                            (int)(mu_[j_] == SENT8));                          \
          } else {                                                             \
            pend##Sx |= 1 << j_;                                               \
          }                                                                    \
        }                                                                      \
        pv##Sx[j_] = v_; rs##Sx[j_] = rs_;                                     \
      }                                                                        \
    }                                                                          \
  }

// spin on pending children: poll the 8B meta word only (one broadcast
// transaction per child per pass); on flip, take rsum and ISSUE the row
// gather (consumed at FIRE under the compiler's auto-waitcnt).
#define RESOLVE_SPIN(Sx)                                                       \
  while (pend##Sx) {                                                           \
    int done_ = 0;                                                             \
    _Pragma("unroll")                                                          \
    for (int j_ = 0; j_ < 6; ++j_)                                             \
      if ((pend##Sx >> j_) & 1) {                                              \
        int idx_ = (j_ < 3) ? left[base##Sx + j_] : right[base##Sx + j_ - 3];  \
        int rr_ = idx_ - N_LEAVES;                                             \
        unsigned long long mu_ = meta_load(meta, rr_);                         \
        if (__all(mu_ != SENT8)) {                                             \
          F2U mm_; mm_.u = mu_;                                                \
          rs##Sx[j_] = mm_.f.x;                                                \
          pv##Sx[j_] = row_gather(P, rr_, lane, (int)(mu_ == SENT8));          \
          done_ |= 1 << j_;                                                    \
        }                                                                      \
      }                                                                        \
    pend##Sx &= ~done_;                                                        \
    if (pend##Sx) __builtin_amdgcn_s_sleep(2);                                 \
  }

// compute + publish wave KK (math identical to r4/r9). Publish protocol:
// row stores -> vmcnt(0) drain (rows at coherence point) -> meta store.
#define FIRE(Sx, KK)                                                           \
  {                                                                            \
    float v0_ = 0.f, v1_ = 0.f;                                                \
    _Pragma("unroll")                                                          \
    for (int jj_ = 0; jj_ < KSPLITS; ++jj_) {                                  \
      float2 a_ = pv##Sx[jj_], b_ = pv##Sx[jj_ + 3];                           \
      float sl_ = rs##Sx[jj_], sr_ = rs##Sx[jj_ + 3], w_ = wq##Sx[jj_];        \
      v0_ += w_ * (onepD * a_.x * b_.x +                                       \
                   T127 * (a_.x * (sr_ - b_.x) + b_.x * (sl_ - a_.x)));        \
      v1_ += w_ * (onepD * a_.y * b_.y +                                       \
                   T127 * (a_.y * (sr_ - b_.y) + b_.y * (sl_ - a_.y)));        \
    }                                                                          \
    v0_ /= denom; v1_ /= denom;                                                \
    float mx_ = fmaxf(v0_, v1_);                                               \
    float tt_ = v0_ + v1_;                                                     \
    _Pragma("unroll")                                                          \
    for (int d_ = 1; d_ < 64; d_ <<= 1) {                                      \
      mx_ = fmaxf(mx_, __shfl_xor(mx_, d_));                                   \
      tt_ += __shfl_xor(tt_, d_);                                              \
    }                                                                          \
    const float safe_ = fmaxf(mx_, EPS);                                       \
    const int row_ = (KK) * WC + c;                                            \
    F2U o_; o_.f = make_float2(v0_ / safe_, v1_ / safe_);                      \
    __hip_atomic_store((unsigned long long*)(P + (size_t)row_ * S) + lane,     \
                       o_.u, __ATOMIC_RELAXED, AGENT);                         \
    asm volatile("s_waitcnt vmcnt(0)" ::: "memory");                           \
    if (lane == 0) {                                                           \
      F2U mo_; mo_.f = make_float2(tt_ / safe_, logf(safe_));                  \
      __hip_atomic_store(&meta[row_], mo_.u, __ATOMIC_RELAXED, AGENT);         \
    }                                                                          \
  }

// ---------------------------------------------------------------------------
// fused: 6144 wavefronts (3 per clade slot, 24 waves/CU). Dataflow protocol
// v2: drained meta-flag publication; consumers poll 8B metas (64x less IF
// poll traffic than row polling), gather rows once after discovery.
// Two-slot ping-pong, in-order fire per wavefront (deadlock-free by
// induction on the globally-minimum unfired wave).
// ---------------------------------------------------------------------------
__global__ __launch_bounds__(TPB, 6) void fused_kernel(
    const float* __restrict__ theta, const float* __restrict__ logw,
    const int* __restrict__ left, const int* __restrict__ right,
    const int* __restrict__ leaf_species, const int* __restrict__ root_ids,
    float* __restrict__ P, unsigned long long* __restrict__ meta,
    float* __restrict__ out) {
    const int lane = threadIdx.x & 63;
    const int w = blockIdx.x * (TPB / 64) + (threadIdx.x >> 6);  // 0..6143
    const int c = w / 3;         // clade slot 0..2047
    const int q = w - 3 * c;     // wave phase 0..2

    // DTL rates + extinction fixed point (e uniform across species ->
    // mean(e) == e bitwise; scalar iteration).
    const float D = exp2f(theta[0]);
    const float L = exp2f(theta[1]);
    const float T = exp2f(theta[2]);
    const float norm = D + L + T + 1.0f;
    float e = L / norm;
#pragma unroll 1
    for (int i = 0; i < E_ITERS; ++i)
        e = (L + D * e * e + T * e * e) / norm;
    const float denom = 1.0f + D * e + T * e;
    const float onepD = 1.0f + D;
    const float T127 = T / 127.0f;

    SLOT_DECL(A) SLOT_DECL(B)

    REFILL(A, q) REFILL(B, q + 3)

#pragma unroll 1
    for (int k = q; k < WAVES; k += 6) {
        RESOLVE_SPIN(A) FIRE(A, k)     REFILL(A, k + 6)
        RESOLVE_SPIN(B) FIRE(B, k + 3) REFILL(B, k + 9)
    }

    // final: per-family ll from the root row's meta (rsum, ls) — one 8B poll.
    // Leaf roots contribute exactly 0 — skipped bitwise. Phase-0 wavefront
    // of slot c handles family c.
    const int r = root_ids[c];
    if (q == 0 && r >= N_LEAVES && lane == 0) {
        const int row = r - N_LEAVES;
        F2U m;
        while ((m.u = __hip_atomic_load(&meta[row], __ATOMIC_RELAXED, AGENT)) == SENT8)
            __builtin_amdgcn_s_sleep(2);
        atomicAdd(out, -(logf(m.f.x + EPS) + m.f.y));
    }
}

// ---------------------------------------------------------------------------
extern "C" void kernel_launch(void* const* d_in, const int* in_sizes, int n_in,
                              void* d_out, int out_size, void* d_ws, size_t ws_size,
                              hipStream_t stream) {
    const float* theta        = (const float*)d_in[0];
    const float* logw         = (const float*)d_in[1];
    const int*   left         = (const int*)d_in[2];
    const int*   right        = (const int*)d_in[3];
    const int*   leaf_species = (const int*)d_in[4];
    const int*   root_ids     = (const int*)d_in[5];
    float* out = (float*)d_out;

    char* ws = (char*)d_ws;
    float* P = (float*)ws;                                        // 25.17 MB (no init needed)
    unsigned long long* meta =
        (unsigned long long*)(ws + (size_t)N_INT * S * 4);        // 0.39 MB (sentinel-init)

    init_kernel<<<(N_INT + 255) / 256, 256, 0, stream>>>(meta, out);
    fused_kernel<<<NBLK, TPB, 0, stream>>>(theta, logw, left, right,
                                           leaf_species, root_ids,
                                           P, meta, out);
}